// Round 13
// baseline (1565.913 us; speedup 1.0000x reference)
//
#include <hip/hip_runtime.h>
#include <stdint.h>

#define BATCH   16
#define NANCH   25200
#define NCLS    80
#define REC     85
#define MAXDET  300
#define TMAX    50
#define NBUCKET 2048
#define FIN     512
#define MREP    16   // measurement repeats

// output offsets (floats)
#define OFF_PB 0
#define OFF_PS 19200
#define OFF_PL 24000
#define OFF_PK 28800
#define OFF_TB 33600
#define OFF_TS 36800
#define OFF_TL 37600
#define OFF_TV 38400

__device__ __forceinline__ float opaque_f(float x) { asm volatile("" : "+v"(x)); return x; }

// ---- Kernel A: score+label, obj-gated; x16 idempotent reps (measured) ----
__global__ __launch_bounds__(256) void kA(const float* __restrict__ logits,
                                          unsigned* __restrict__ confout,
                                          unsigned* __restrict__ labout) {
    const int wid  = (blockIdx.x * 256 + threadIdx.x) >> 6;
    const int lane = threadIdx.x & 63;
    const int t    = lane >> 2;
    const int j    = lane & 3;
    const int a    = wid * 16 + t;
#pragma unroll 1
    for (int rep = 0; rep < MREP; ++rep) {
        const float obj = logits[(size_t)a * REC + 4];
        unsigned cf = 0u;
        if (obj > 0.8f) {
            const float* cls = logits + (size_t)a * REC + 5 + j * 20;
            float v[20];
#pragma unroll
            for (int i = 0; i < 5; ++i) {
                float4 q = *(const float4*)(cls + 4 * i);
                v[4*i+0] = q.x; v[4*i+1] = q.y; v[4*i+2] = q.z; v[4*i+3] = q.w;
            }
            float m = v[0];
#pragma unroll
            for (int i = 1; i < 20; ++i) m = fmaxf(m, v[i]);
            m = fmaxf(m, __shfl_xor(m, 1));
            m = fmaxf(m, __shfl_xor(m, 2));
            int lc = 255;
#pragma unroll
            for (int i = 0; i < 20; ++i) lc = min(lc, (v[i] == m) ? (j * 20 + i) : 255);
            lc = min(lc, __shfl_xor(lc, 1));
            lc = min(lc, __shfl_xor(lc, 2));
            const float conf = obj * m;
            cf = (conf > 0.8f) ? __float_as_uint(conf) : 0u;
            if (j == 0) labout[a] = (unsigned)lc;
        }
        if (j == 0) confout[a] = cf;
        asm volatile("" ::: "memory");
    }
}

// ---- kVar<V>: cumulative phase prefixes of kFused, x16 reps, scratch out ----
template<int V>
__global__ __launch_bounds__(1024) void kVar(const float* __restrict__ logits,
                                             const unsigned* __restrict__ confbits,
                                             const unsigned* __restrict__ labels,
                                             unsigned long long* __restrict__ dbg) {
    __shared__ unsigned hist[NBUCKET];
    __shared__ unsigned long long fin[FIN];
    __shared__ unsigned long long srt[MAXDET];
    __shared__ float bx1[MAXDET], by1[MAXDET], bx2[MAXDET], by2[MAXDET];
    __shared__ float sar[MAXDET];
    __shared__ unsigned supp[MAXDET * 10];
    __shared__ unsigned keepw[10];
    __shared__ int sTb, sCnt;
    const int b = blockIdx.x;
    const int tid = threadIdx.x;
    const int lane = tid & 63;
    const int w = tid >> 6;
    unsigned long long* db = dbg + (size_t)b * 4096;
    const unsigned* cb = confbits + (size_t)b * NANCH;
    const uint4* cb4 = (const uint4*)cb;
#pragma unroll 1
    for (int rep = 0; rep < MREP; ++rep) {
        // init
        for (int i = tid; i < NBUCKET; i += 1024) hist[i] = 0u;
        if (tid < MAXDET) srt[tid] = 0ull;
        if (tid == 0) sCnt = 0;
        __syncthreads();
        // histogram
#pragma unroll 1
        for (int i = tid; i < NANCH / 4; i += 1024) {
            uint4 u = cb4[i];
            unsigned w0 = u.x, w1 = u.y, w2 = u.z, w3 = u.w;
            if (w0) { unsigned bk = (w0 - 0x3F4CCCCDu) >> 11; if (bk > NBUCKET-1u) bk = NBUCKET-1u; atomicAdd(&hist[bk], 1u); }
            if (w1) { unsigned bk = (w1 - 0x3F4CCCCDu) >> 11; if (bk > NBUCKET-1u) bk = NBUCKET-1u; atomicAdd(&hist[bk], 1u); }
            if (w2) { unsigned bk = (w2 - 0x3F4CCCCDu) >> 11; if (bk > NBUCKET-1u) bk = NBUCKET-1u; atomicAdd(&hist[bk], 1u); }
            if (w3) { unsigned bk = (w3 - 0x3F4CCCCDu) >> 11; if (bk > NBUCKET-1u) bk = NBUCKET-1u; atomicAdd(&hist[bk], 1u); }
        }
        __syncthreads();
        // threshold
        if (tid < 64) {
            const int l = tid;
            unsigned sup = 0u;
            for (int jj = 0; jj < 32; ++jj) sup += hist[l * 32 + jj];
            unsigned ss = sup;
            for (int off = 1; off < 64; off <<= 1) {
                unsigned vv = __shfl_down(ss, off);
                ss += (l + off < 64) ? vv : 0u;
            }
            bool ge = ss >= MAXDET;
            unsigned long long mask = __ballot(ge);
            int sstar = (mask == 0ull) ? 0 : (63 - __clzll(mask));
            unsigned tail = (sstar < 63) ? __shfl(ss, sstar + 1) : 0u;
            unsigned h = (l < 32) ? hist[sstar * 32 + l] : 0u;
            unsigned s2 = h;
            for (int off = 1; off < 32; off <<= 1) {
                unsigned vv = __shfl_down(s2, off);
                s2 += (l + off < 32) ? vv : 0u;
            }
            bool ge2 = (l < 32) && (s2 + tail >= MAXDET);
            unsigned long long m2 = __ballot(ge2);
            int lstar = (m2 == 0ull) ? 0 : (63 - __clzll(m2));
            if (l == 0) sTb = sstar * 32 + lstar;
        }
        __syncthreads();
        if (tid == 0) db[0] = (unsigned long long)(unsigned)sTb;
        int fc = 0;
        if constexpr (V >= 2) {
            const int tb = sTb;
#pragma unroll 1
            for (int i = tid; i < NANCH / 4; i += 1024) {
                uint4 u = cb4[i];
                unsigned wsv[4] = {u.x, u.y, u.z, u.w};
#pragma unroll
                for (int c = 0; c < 4; ++c) {
                    unsigned bits = wsv[c];
                    unsigned bk = (bits - 0x3F4CCCCDu) >> 11;
                    if (bk > NBUCKET - 1u) bk = NBUCKET - 1u;
                    bool pass = bits && ((int)bk >= tb);
                    unsigned long long mk = __ballot(pass);
                    if (mk) {
                        int base = 0;
                        if (lane == 0) base = atomicAdd(&sCnt, __popcll(mk));
                        base = __shfl(base, 0);
                        if (pass) {
                            int p = base + __popcll(mk & ((1ull << lane) - 1ull));
                            if (p < FIN)
                                fin[p] = ((unsigned long long)bits << 32) |
                                         (unsigned)(0xFFFFFFFFu - (unsigned)(i * 4 + c));
                        }
                    }
                }
            }
            __syncthreads();
            fc = (sCnt < FIN) ? sCnt : FIN;
            if (tid < FIN) db[8 + tid] = (tid < fc) ? fin[tid] : 0ull;
        }
        if constexpr (V >= 3) {
            if (tid < fc) {
                unsigned long long k = fin[tid];
                int r = 0;
                for (int jj = 0; jj < fc; ++jj) r += (fin[jj] > k) ? 1 : 0;
                if (r < MAXDET) srt[r] = k;
            }
            __syncthreads();
            if (tid < MAXDET) db[600 + tid] = srt[tid];
        }
        if constexpr (V >= 4) {
            if (tid < MAXDET) {
                unsigned long long key = srt[tid];
                float score = __uint_as_float((unsigned)(key >> 32));
                unsigned n = 0xFFFFFFFFu - (unsigned)(key & 0xFFFFFFFFull);
                if (n >= NANCH) n = 0;
                const size_t ga = (size_t)b * NANCH + n;
                float4 bq = *(const float4*)(logits + ga * REC);
                unsigned lab = labels[ga];
                float hw = opaque_f(bq.z * 0.5f);
                float hh = opaque_f(bq.w * 0.5f);
                float x1 = bq.x - hw, y1 = bq.y - hh, x2 = bq.x + hw, y2 = bq.y + hh;
                bx1[tid] = x1; by1[tid] = y1; bx2[tid] = x2; by2[tid] = y2;
                sar[tid] = (x2 - x1) * (y2 - y1);
                db[1000 + 2 * tid]     = ((unsigned long long)__float_as_uint(x1) << 32) | __float_as_uint(y1);
                db[1000 + 2 * tid + 1] = ((unsigned long long)__float_as_uint(x2) << 32) | __float_as_uint(y2);
                db[1700 + tid] = ((unsigned long long)__float_as_uint(score) << 32) | lab;
            }
            __syncthreads();
        }
        if constexpr (V >= 5) {
            for (int i = w; i < MAXDET; i += 16) {
                float p1 = bx1[i], q1 = by1[i], p2 = bx2[i], q2 = by2[i];
                float ai = sar[i];
#pragma unroll
                for (int c = 0; c < 5; ++c) {
                    int jj = c * 64 + lane;
                    bool pass = false;
                    if (jj < MAXDET && jj > i) {
                        float ltx = fmaxf(p1, bx1[jj]);
                        float lty = fmaxf(q1, by1[jj]);
                        float rbx = fminf(p2, bx2[jj]);
                        float rby = fminf(q2, by2[jj]);
                        float wx = fmaxf(rbx - ltx, 0.0f);
                        float wy = fmaxf(rby - lty, 0.0f);
                        float inter = wx * wy;
                        float iou = inter / (ai + sar[jj] - inter + 1e-9f);
                        pass = (iou > 0.4f);
                    }
                    unsigned long long mk = __ballot(pass);
                    if (lane == 0)  supp[i * 10 + 2 * c]     = (unsigned)mk;
                    if (lane == 32) supp[i * 10 + 2 * c + 1] = (unsigned)(mk >> 32);
                }
            }
            __syncthreads();
            if (tid < 64) {
                int q = tid;
                unsigned kw = (q < 10) ? ((q == 9) ? 0xFFFu : 0xFFFFFFFFu) : 0u;
                unsigned nextrow = (q < 10) ? supp[q] : 0u;
                for (int i = 0; i < MAXDET; ++i) {
                    unsigned rowq = nextrow;
                    if (q < 10 && i + 1 < MAXDET) nextrow = supp[(i + 1) * 10 + q];
                    bool mybit = (q == (i >> 5)) && ((kw >> (i & 31)) & 1u);
                    if (__ballot(mybit)) kw &= ~rowq;
                }
                if (q < 10) keepw[q] = kw;
            }
            __syncthreads();
            if (tid < 10) db[1990 + tid] = keepw[tid];
        }
        __syncthreads();
        asm volatile("" ::: "memory");
    }
}

// ---- kFused: REAL output pass (verbatim R12) ----
__global__ __launch_bounds__(1024) void kFused(const float* __restrict__ logits,
                                               const unsigned* __restrict__ confbits,
                                               const unsigned* __restrict__ labels,
                                               const float* __restrict__ targets,
                                               const int* __restrict__ tlen,
                                               float* __restrict__ out) {
    __shared__ unsigned hist[NBUCKET];
    __shared__ unsigned long long fin[FIN];
    __shared__ unsigned long long srt[MAXDET];
    __shared__ float bx1[MAXDET], by1[MAXDET], bx2[MAXDET], by2[MAXDET];
    __shared__ float sar[MAXDET];
    __shared__ unsigned supp[MAXDET * 10];
    __shared__ unsigned keepw[10];
    __shared__ int sTb, sCnt;
    const int b = blockIdx.x;
    const int tid = threadIdx.x;
    const int lane = tid & 63;
    const int w = tid >> 6;

    if (tid >= 512 && tid < 512 + TMAX) {
        int t = tid - 512;
        bool is64 = (tlen[1] == 0) && (tlen[3] == 0) && (tlen[5] == 0);
        int len = is64 ? tlen[2 * b] : tlen[b];
        const float* r = targets + ((size_t)b * TMAX + t) * 6;
        float cx = r[0], cy = r[1], wd = r[2], h = r[3], sc = r[4], lb = r[5];
        float hw = opaque_f(wd * 0.5f);
        float hh = opaque_f(h * 0.5f);
        size_t o = (size_t)b * TMAX + t;
        out[OFF_TB + o * 4 + 0] = cx - hw;
        out[OFF_TB + o * 4 + 1] = cy - hh;
        out[OFF_TB + o * 4 + 2] = cx + hw;
        out[OFF_TB + o * 4 + 3] = cy + hh;
        out[OFF_TS + o] = sc;
        out[OFF_TL + o] = (float)(int)lb;
        out[OFF_TV + o] = (t < len) ? 1.0f : 0.0f;
    }

    for (int i = tid; i < NBUCKET; i += 1024) hist[i] = 0u;
    if (tid < MAXDET) srt[tid] = 0ull;
    if (tid == 0) sCnt = 0;
    __syncthreads();

    const unsigned* cb = confbits + (size_t)b * NANCH;
    const uint4* cb4 = (const uint4*)cb;
#pragma unroll 1
    for (int i = tid; i < NANCH / 4; i += 1024) {
        uint4 u = cb4[i];
        unsigned w0 = u.x, w1 = u.y, w2 = u.z, w3 = u.w;
        if (w0) { unsigned bk = (w0 - 0x3F4CCCCDu) >> 11; if (bk > NBUCKET-1u) bk = NBUCKET-1u; atomicAdd(&hist[bk], 1u); }
        if (w1) { unsigned bk = (w1 - 0x3F4CCCCDu) >> 11; if (bk > NBUCKET-1u) bk = NBUCKET-1u; atomicAdd(&hist[bk], 1u); }
        if (w2) { unsigned bk = (w2 - 0x3F4CCCCDu) >> 11; if (bk > NBUCKET-1u) bk = NBUCKET-1u; atomicAdd(&hist[bk], 1u); }
        if (w3) { unsigned bk = (w3 - 0x3F4CCCCDu) >> 11; if (bk > NBUCKET-1u) bk = NBUCKET-1u; atomicAdd(&hist[bk], 1u); }
    }
    __syncthreads();

    if (tid < 64) {
        const int l = tid;
        unsigned sup = 0u;
        for (int j = 0; j < 32; ++j) sup += hist[l * 32 + j];
        unsigned ss = sup;
        for (int off = 1; off < 64; off <<= 1) {
            unsigned v = __shfl_down(ss, off);
            ss += (l + off < 64) ? v : 0u;
        }
        bool ge = ss >= MAXDET;
        unsigned long long mask = __ballot(ge);
        int sstar = (mask == 0ull) ? 0 : (63 - __clzll(mask));
        unsigned tail = (sstar < 63) ? __shfl(ss, sstar + 1) : 0u;
        unsigned h = (l < 32) ? hist[sstar * 32 + l] : 0u;
        unsigned s2 = h;
        for (int off = 1; off < 32; off <<= 1) {
            unsigned v = __shfl_down(s2, off);
            s2 += (l + off < 32) ? v : 0u;
        }
        bool ge2 = (l < 32) && (s2 + tail >= MAXDET);
        unsigned long long m2 = __ballot(ge2);
        int lstar = (m2 == 0ull) ? 0 : (63 - __clzll(m2));
        if (l == 0) sTb = sstar * 32 + lstar;
    }
    __syncthreads();

    const int tb = sTb;
#pragma unroll 1
    for (int i = tid; i < NANCH / 4; i += 1024) {
        uint4 u = cb4[i];
        unsigned wsv[4] = {u.x, u.y, u.z, u.w};
#pragma unroll
        for (int c = 0; c < 4; ++c) {
            unsigned bits = wsv[c];
            unsigned bk = (bits - 0x3F4CCCCDu) >> 11;
            if (bk > NBUCKET - 1u) bk = NBUCKET - 1u;
            bool pass = bits && ((int)bk >= tb);
            unsigned long long mk = __ballot(pass);
            if (mk) {
                int base = 0;
                if (lane == 0) base = atomicAdd(&sCnt, __popcll(mk));
                base = __shfl(base, 0);
                if (pass) {
                    int p = base + __popcll(mk & ((1ull << lane) - 1ull));
                    if (p < FIN)
                        fin[p] = ((unsigned long long)bits << 32) |
                                 (unsigned)(0xFFFFFFFFu - (unsigned)(i * 4 + c));
                }
            }
        }
    }
    __syncthreads();
    const int fc = (sCnt < FIN) ? sCnt : FIN;

    if (tid < fc) {
        unsigned long long k = fin[tid];
        int r = 0;
        for (int j = 0; j < fc; ++j) r += (fin[j] > k) ? 1 : 0;
        if (r < MAXDET) srt[r] = k;
    }
    __syncthreads();

    if (tid < MAXDET) {
        unsigned long long key = srt[tid];
        float score = __uint_as_float((unsigned)(key >> 32));
        unsigned n = 0xFFFFFFFFu - (unsigned)(key & 0xFFFFFFFFull);
        if (n >= NANCH) n = 0;
        const size_t ga = (size_t)b * NANCH + n;
        float4 bq = *(const float4*)(logits + ga * REC);
        unsigned lab = labels[ga];
        float hw = opaque_f(bq.z * 0.5f);
        float hh = opaque_f(bq.w * 0.5f);
        float x1 = bq.x - hw, y1 = bq.y - hh, x2 = bq.x + hw, y2 = bq.y + hh;
        bx1[tid] = x1; by1[tid] = y1; bx2[tid] = x2; by2[tid] = y2;
        sar[tid] = (x2 - x1) * (y2 - y1);
        size_t o = (size_t)(b * MAXDET + tid);
        out[OFF_PB + o * 4 + 0] = x1;
        out[OFF_PB + o * 4 + 1] = y1;
        out[OFF_PB + o * 4 + 2] = x2;
        out[OFF_PB + o * 4 + 3] = y2;
        out[OFF_PS + o] = score;
        out[OFF_PL + o] = (float)lab;
    }
    __syncthreads();

    for (int i = w; i < MAXDET; i += 16) {
        float p1 = bx1[i], q1 = by1[i], p2 = bx2[i], q2 = by2[i];
        float ai = sar[i];
#pragma unroll
        for (int c = 0; c < 5; ++c) {
            int j = c * 64 + lane;
            bool pass = false;
            if (j < MAXDET && j > i) {
                float ltx = fmaxf(p1, bx1[j]);
                float lty = fmaxf(q1, by1[j]);
                float rbx = fminf(p2, bx2[j]);
                float rby = fminf(q2, by2[j]);
                float wx = fmaxf(rbx - ltx, 0.0f);
                float wy = fmaxf(rby - lty, 0.0f);
                float inter = wx * wy;
                float iou = inter / (ai + sar[j] - inter + 1e-9f);
                pass = (iou > 0.4f);
            }
            unsigned long long mk = __ballot(pass);
            if (lane == 0)  supp[i * 10 + 2 * c]     = (unsigned)mk;
            if (lane == 32) supp[i * 10 + 2 * c + 1] = (unsigned)(mk >> 32);
        }
    }
    __syncthreads();

    if (tid < 64) {
        int q = tid;
        unsigned kw = (q < 10) ? ((q == 9) ? 0xFFFu : 0xFFFFFFFFu) : 0u;
        unsigned nextrow = (q < 10) ? supp[q] : 0u;
        for (int i = 0; i < MAXDET; ++i) {
            unsigned rowq = nextrow;
            if (q < 10 && i + 1 < MAXDET) nextrow = supp[(i + 1) * 10 + q];
            bool mybit = (q == (i >> 5)) && ((kw >> (i & 31)) & 1u);
            if (__ballot(mybit)) kw &= ~rowq;
        }
        if (q < 10) keepw[q] = kw;
    }
    __syncthreads();
    if (tid < MAXDET)
        out[OFF_PK + (size_t)b * MAXDET + tid] =
            ((keepw[tid >> 5] >> (tid & 31)) & 1u) ? 1.0f : 0.0f;
}

extern "C" void kernel_launch(void* const* d_in, const int* in_sizes, int n_in,
                              void* d_out, int out_size, void* d_ws, size_t ws_size,
                              hipStream_t stream) {
    const float* logits  = (const float*)d_in[0];
    const float* targets = (const float*)d_in[1];
    const int*   tlen    = (const int*)d_in[2];
    float* out = (float*)d_out;
    char* ws = (char*)d_ws;
    unsigned* confbits = (unsigned*)ws;                                 // 403200 u32
    unsigned* labels   = (unsigned*)(ws + (size_t)BATCH * NANCH * 4);   // 403200 u32
    unsigned long long* dbg =
        (unsigned long long*)(ws + (size_t)BATCH * NANCH * 8);          // 16*4096 u64

    hipLaunchKernelGGL(kA, dim3(6300), dim3(256), 0, stream, logits, confbits, labels);
    kVar<1><<<dim3(BATCH), dim3(1024), 0, stream>>>(logits, confbits, labels, dbg);
    kVar<2><<<dim3(BATCH), dim3(1024), 0, stream>>>(logits, confbits, labels, dbg);
    kVar<3><<<dim3(BATCH), dim3(1024), 0, stream>>>(logits, confbits, labels, dbg);
    kVar<4><<<dim3(BATCH), dim3(1024), 0, stream>>>(logits, confbits, labels, dbg);
    kVar<5><<<dim3(BATCH), dim3(1024), 0, stream>>>(logits, confbits, labels, dbg);
    hipLaunchKernelGGL(kFused, dim3(BATCH), dim3(1024), 0, stream,
                       logits, confbits, labels, targets, tlen, out);
}